// Round 1
// 6262.630 us; speedup vs baseline: 2.0755x; 2.0755x over previous
//
#include <hip/hip_runtime.h>

#define L_   8
#define H_   16
#define E_   1024
#define V_   32000
#define T_   1024
#define B_   2
#define HS_  64
#define DFF_ 4096
#define MROWS (B_*T_)   // 2048
#define QKVS 3072       // fused q|k|v row stride

typedef float    f32x4 __attribute__((ext_vector_type(4)));
typedef _Float16 h8    __attribute__((ext_vector_type(8)));
typedef _Float16 h4    __attribute__((ext_vector_type(4)));

// async global->LDS, 16B per lane: LDS dst = wave-uniform base + lane*16 (linear)
__device__ __forceinline__ void gload16(const void* g, void* l)
{
    __builtin_amdgcn_global_load_lds((const __attribute__((address_space(1))) unsigned int*)g,
                                     (__attribute__((address_space(3))) unsigned int*)l,
                                     16, 0, 0);
}

// ---------------------------------------------------------------------------
// Embedding: x[b*T+t, e] = tok_emb[idx[b,t], e] + pos_emb[t, e]   (fp32)
// ---------------------------------------------------------------------------
__global__ __launch_bounds__(256) void embed_k(const int* __restrict__ idx,
                                               const float* __restrict__ tok,
                                               const float* __restrict__ pos,
                                               float* __restrict__ x)
{
    const int bt = blockIdx.x;
    const int t  = bt & (T_ - 1);
    const int token = idx[bt];
    const int e = threadIdx.x * 4;
    float4 tv = *(const float4*)(tok + (size_t)token * E_ + e);
    float4 pv = *(const float4*)(pos + (size_t)t * E_ + e);
    *(float4*)(x + (size_t)bt * E_ + e) =
        make_float4(tv.x + pv.x, tv.y + pv.y, tv.z + pv.z, tv.w + pv.w);
}

// ---------------------------------------------------------------------------
// LayerNorm fp32 in -> fp16 out (consumed only as GEMM A operand)
// ---------------------------------------------------------------------------
__global__ __launch_bounds__(256) void ln_k(const float* __restrict__ x,
                                            const float* __restrict__ g,
                                            const float* __restrict__ b,
                                            _Float16* __restrict__ out)
{
    const int row = blockIdx.x;
    const int tid = threadIdx.x;
    const float* xr = x + (size_t)row * E_;
    float4 v = ((const float4*)xr)[tid];
    float s  = v.x + v.y + v.z + v.w;
    float ss = v.x*v.x + v.y*v.y + v.z*v.z + v.w*v.w;
#pragma unroll
    for (int off = 32; off > 0; off >>= 1) {
        s  += __shfl_down(s,  off);
        ss += __shfl_down(ss, off);
    }
    __shared__ float sm[4], sm2[4];
    if ((tid & 63) == 0) { sm[tid >> 6] = s; sm2[tid >> 6] = ss; }
    __syncthreads();
    s  = sm[0] + sm[1] + sm[2] + sm[3];
    ss = sm2[0] + sm2[1] + sm2[2] + sm2[3];
    const float mean = s * (1.f / E_);
    const float var  = ss * (1.f / E_) - mean * mean;
    const float rstd = rsqrtf(var + 1e-5f);
    float4 gv = ((const float4*)g)[tid];
    float4 bv = ((const float4*)b)[tid];
    h4 o;
    o[0] = (_Float16)((v.x - mean) * rstd * gv.x + bv.x);
    o[1] = (_Float16)((v.y - mean) * rstd * gv.y + bv.y);
    o[2] = (_Float16)((v.z - mean) * rstd * gv.z + bv.z);
    o[3] = (_Float16)((v.w - mean) * rstd * gv.w + bv.w);
    ((h4*)(out + (size_t)row * E_))[tid] = o;
}

// ---------------------------------------------------------------------------
// Transpose + fp32->fp16 convert:  W[K,N] (row-major) -> out[N][K] fp16.
// 32x32 tiles via LDS, both sides coalesced.
// ---------------------------------------------------------------------------
__global__ __launch_bounds__(256) void trcvt_k(const float* __restrict__ W,
                                               _Float16* __restrict__ out,
                                               int Kd, int Nd)
{
    __shared__ float s[32][33];
    const int tx = threadIdx.x & 31, ty = threadIdx.x >> 5;   // 32 x 8
    const int n = blockIdx.x * 32 + tx;
    const int k0 = blockIdx.y * 32;
#pragma unroll
    for (int j = 0; j < 4; ++j)
        s[ty + j*8][tx] = W[(size_t)(k0 + ty + j*8) * Nd + n];
    __syncthreads();
    const int k = k0 + tx;
    const int nb = blockIdx.x * 32;
#pragma unroll
    for (int j = 0; j < 4; ++j)
        out[(size_t)(nb + ty + j*8) * Kd + k] = (_Float16)s[tx][ty + j*8];
}

// ---------------------------------------------------------------------------
// fp16 MFMA GEMM (m97 structure): C[m,n] = sum_k A[m,k] * Bt[n,k]
//   A:  fp16 [M][K]          (K-contig)
//   Bt: fp16 [N][K] (!BCONV) or fp32 [N][K] (BCONV, converted during staging)
// 128 x BN tile, BK=32, 4 waves (2x2), v_mfma_f32_16x16x32_f16, fp32 accum.
// Epilogue: optional fp32 bias[n], fp32 residual add, relu, fp16 or fp32 out.
// MXF: blockIdx.x indexes M (for the huge-N lm_head so B is read once).
// ---------------------------------------------------------------------------
template<int BN, bool BCONV, bool BIAS, bool RELU, bool RES, bool OUTH, bool MXF>
__global__ __launch_bounds__(256) void hgemm_k(const _Float16* __restrict__ A,
                                               const void* __restrict__ Bw,
                                               const float* __restrict__ bias,
                                               const float* __restrict__ res,
                                               void* __restrict__ Cp,
                                               int M, int N, int K)
{
    static_assert(BN == 128 || BN == 64, "BN");
    static_assert(!BCONV || BN == 128, "BCONV needs BN=128");
    constexpr int BM = 128, BK = 32;
    constexpr int FN = BN / 32;           // B fragments per wave (4 or 2)
    __shared__ __attribute__((aligned(16))) _Float16 As[BM * BK];
    __shared__ __attribute__((aligned(16))) _Float16 Bs[BN * BK];

    const int tid  = threadIdx.x;
    const int wave = tid >> 6;
    const int lane = tid & 63;
    const int m0 = (MXF ? blockIdx.x : blockIdx.y) * BM;
    const int n0 = (MXF ? blockIdx.y : blockIdx.x) * BN;
    const int wm = (wave >> 1) * 64;            // wave tile: 64 x BN/2
    const int wn = (wave & 1) * (BN / 2);
    const int fr = lane & 15;                   // frag row (A) / col (B)
    const int fk = (lane >> 4) * 8;             // frag k offset (8 contiguous)

    // A staging: wave w, instr i covers rows w*32 + i*16 + (lane>>2), 16B/lane
    const _Float16* ga = A + (size_t)(m0 + wave*32 + (lane >> 2)) * K + (lane & 3) * 8;
    _Float16* lA0 = As + (wave*32) * BK;
    _Float16* lA1 = As + (wave*32 + 16) * BK;

    const _Float16* gb = nullptr;
    _Float16* lB0 = nullptr; _Float16* lB1 = nullptr;
    const float* gbc = nullptr;
    int brow = 0, bkh = 0;
    if constexpr (!BCONV) {
        const _Float16* B16 = (const _Float16*)Bw;
        if constexpr (BN == 128) {
            gb  = B16 + (size_t)(n0 + wave*32 + (lane >> 2)) * K + (lane & 3) * 8;
            lB0 = Bs + (wave*32) * BK;
            lB1 = Bs + (wave*32 + 16) * BK;
        } else {
            gb  = B16 + (size_t)(n0 + wave*16 + (lane >> 2)) * K + (lane & 3) * 8;
            lB0 = Bs + (wave*16) * BK;
        }
    } else {
        brow = tid >> 1;                 // 0..127
        bkh  = (tid & 1) * 16;           // k half
        gbc  = (const float*)Bw + (size_t)(n0 + brow) * K + bkh;
    }

    f32x4 acc[4][FN];
#pragma unroll
    for (int i = 0; i < 4; ++i)
#pragma unroll
        for (int j = 0; j < FN; ++j) acc[i][j] = (f32x4){0.f, 0.f, 0.f, 0.f};

    for (int k0 = 0; k0 < K; k0 += BK) {
        gload16(ga + k0,                 lA0);
        gload16(ga + k0 + 16*(size_t)K,  lA1);
        if constexpr (!BCONV) {
            gload16(gb + k0, lB0);
            if constexpr (BN == 128) gload16(gb + k0 + 16*(size_t)K, lB1);
        } else {
            const float4* s4 = (const float4*)(gbc + k0);
            float4 f0 = s4[0], f1 = s4[1], f2 = s4[2], f3 = s4[3];
            h8 v0 = { (_Float16)f0.x,(_Float16)f0.y,(_Float16)f0.z,(_Float16)f0.w,
                      (_Float16)f1.x,(_Float16)f1.y,(_Float16)f1.z,(_Float16)f1.w };
            h8 v1 = { (_Float16)f2.x,(_Float16)f2.y,(_Float16)f2.z,(_Float16)f2.w,
                      (_Float16)f3.x,(_Float16)f3.y,(_Float16)f3.z,(_Float16)f3.w };
            *(h8*)&Bs[brow*BK + bkh]     = v0;
            *(h8*)&Bs[brow*BK + bkh + 8] = v1;
        }
        __syncthreads();   // drains vmcnt (gload) + lgkm (ds_write)

        h8 af[4], bf[FN];
#pragma unroll
        for (int i = 0; i < 4; ++i)
            af[i] = *(const h8*)&As[(wm + i*16 + fr)*BK + fk];
#pragma unroll
        for (int j = 0; j < FN; ++j)
            bf[j] = *(const h8*)&Bs[(wn + j*16 + fr)*BK + fk];
#pragma unroll
        for (int i = 0; i < 4; ++i)
#pragma unroll
            for (int j = 0; j < FN; ++j)
                acc[i][j] = __builtin_amdgcn_mfma_f32_16x16x32_f16(af[i], bf[j], acc[i][j], 0, 0, 0);
        __syncthreads();
    }

    // C/D layout: col = lane&15, row = (lane>>4)*4 + r
#pragma unroll
    for (int i = 0; i < 4; ++i) {
#pragma unroll
        for (int r = 0; r < 4; ++r) {
            const int m = m0 + wm + i*16 + (lane >> 4)*4 + r;
#pragma unroll
            for (int j = 0; j < FN; ++j) {
                const int n = n0 + wn + j*16 + fr;
                float v = acc[i][j][r];
                if constexpr (BIAS) v += bias[n];
                if constexpr (RES)  v += res[(size_t)m * N + n];
                if constexpr (RELU) v = fmaxf(v, 0.f);
                if constexpr (OUTH) ((_Float16*)Cp)[(size_t)m * N + n] = (_Float16)v;
                else                ((float*)Cp)[(size_t)m * N + n] = v;
            }
        }
    }
}

// ---------------------------------------------------------------------------
// Flash attention (causal), fp32. One block per (b, h, q-tile of 64 rows).
// q/k/v live in fused qkv buffer [B*T, 3072]: q at col 0, k at 1024, v at 2048.
// Output fp16 [B*T, E].
// ---------------------------------------------------------------------------
__global__ __launch_bounds__(256) void attn_k(const float* __restrict__ qkv,
                                              _Float16* __restrict__ o)
{
    const int qt = blockIdx.x;   // 0..15
    const int h  = blockIdx.y;   // 0..15
    const int b  = blockIdx.z;   // 0..1
    const int tid = threadIdx.x;

    __shared__ float Qs[64][65], Ks[64][65], Vs[64][65], Ss[64][65];
    __shared__ float m_i[64], l_i[64], alph[64];

    const int r  = tid >> 2;
    const int c0 = (tid & 3) * 16;
    const size_t qbase = ((size_t)(b * T_ + qt * 64)) * QKVS + h * HS_;

    for (int i2 = tid; i2 < 64 * 64; i2 += 256) {
        int rr = i2 >> 6, d = i2 & 63;
        Qs[rr][d] = qkv[qbase + (size_t)rr * QKVS + d];
    }
    if (tid < 64) { m_i[tid] = -1e30f; l_i[tid] = 0.f; }
    float O[16];
#pragma unroll
    for (int c = 0; c < 16; ++c) O[c] = 0.f;

    const int qglob = qt * 64 + r;

    for (int kt = 0; kt <= qt; ++kt) {
        __syncthreads();
        const size_t kbase = ((size_t)(b * T_ + kt * 64)) * QKVS + h * HS_;
        for (int i2 = tid; i2 < 64 * 64; i2 += 256) {
            int j = i2 >> 6, d = i2 & 63;
            Ks[j][d] = qkv[kbase + 1024 + (size_t)j * QKVS + d];
            Vs[j][d] = qkv[kbase + 2048 + (size_t)j * QKVS + d];
        }
        __syncthreads();

#pragma unroll 1
        for (int jj = 0; jj < 16; ++jj) {
            const int j = c0 + jj;
            float s = 0.f;
#pragma unroll
            for (int d = 0; d < 64; ++d) s = fmaf(Qs[r][d], Ks[j][d], s);
            const int jg = kt * 64 + j;
            Ss[r][j] = (jg <= qglob) ? s * 0.125f : -1e30f;
        }
        __syncthreads();

        if (tid < 64) {
            float tm = -1e30f;
            for (int j = 0; j < 64; ++j) tm = fmaxf(tm, Ss[tid][j]);
            const float mn = fmaxf(m_i[tid], tm);
            const float al = __expf(m_i[tid] - mn);
            float sum = 0.f;
            for (int j = 0; j < 64; ++j) {
                float p = __expf(Ss[tid][j] - mn);
                Ss[tid][j] = p;
                sum += p;
            }
            l_i[tid]  = l_i[tid] * al + sum;
            m_i[tid]  = mn;
            alph[tid] = al;
        }
        __syncthreads();

        const float al = alph[r];
#pragma unroll
        for (int c = 0; c < 16; ++c) O[c] *= al;
#pragma unroll 1
        for (int j = 0; j < 64; ++j) {
            const float p = Ss[r][j];
#pragma unroll
            for (int c = 0; c < 16; ++c) O[c] = fmaf(p, Vs[j][c0 + c], O[c]);
        }
    }

    const float inv = 1.f / l_i[r];
    const size_t obase = ((size_t)(b * T_ + qt * 64 + r)) * E_ + h * HS_ + c0;
#pragma unroll
    for (int c = 0; c < 16; ++c)
        o[obase + c] = (_Float16)(O[c] * inv);
}

// ---------------------------------------------------------------------------
// Launch
// ---------------------------------------------------------------------------
extern "C" void kernel_launch(void* const* d_in, const int* in_sizes, int n_in,
                              void* d_out, int out_size, void* d_ws, size_t ws_size,
                              hipStream_t stream)
{
    const int*   idx  = (const int*)  d_in[0];
    const float* tok  = (const float*)d_in[1];
    const float* pos  = (const float*)d_in[2];
    const float* Wq   = (const float*)d_in[3];
    const float* Wk   = (const float*)d_in[4];
    const float* Wv   = (const float*)d_in[5];
    const float* Wo   = (const float*)d_in[6];
    const float* bo   = (const float*)d_in[7];
    const float* W1   = (const float*)d_in[8];
    const float* b1   = (const float*)d_in[9];
    const float* W2   = (const float*)d_in[10];
    const float* b2   = (const float*)d_in[11];
    const float* ln1g = (const float*)d_in[12];
    const float* ln1b = (const float*)d_in[13];
    const float* ln2g = (const float*)d_in[14];
    const float* ln2b = (const float*)d_in[15];
    const float* lnfg = (const float*)d_in[16];
    const float* lnfb = (const float*)d_in[17];
    const float* lmb  = (const float*)d_in[18];

    // workspace layout (48 MB total, proven available by previous kernel):
    //  [ 0, 8M)  x    fp32 [2048][1024]  residual
    //  [ 8,12M)  hbf  fp16 [2048][1024]  LN out
    //  [12,36M)  qkv  fp32 [2048][3072]  (mid fp16 [2048][4096] aliases, 16 MB)
    //  [36,40M)  ob   fp16 [2048][1024]  attn out
    //  [40,48M)  wT   fp16 weight scratch (max 8 MB: W1t/W2t)
    char* w = (char*)d_ws;
    float*    x   = (float*)w;
    _Float16* hbf = (_Float16*)(w + ((size_t)8  << 20));
    float*    qkv = (float*)   (w + ((size_t)12 << 20));
    _Float16* mid = (_Float16*)(w + ((size_t)12 << 20));
    _Float16* ob  = (_Float16*)(w + ((size_t)36 << 20));
    _Float16* wT  = (_Float16*)(w + ((size_t)40 << 20));

    const dim3 blk(256);

    embed_k<<<MROWS, blk, 0, stream>>>(idx, tok, pos, x);

    for (int l = 0; l < L_; ++l) {
        const size_t wE = (size_t)l * E_ * E_;

        ln_k<<<MROWS, blk, 0, stream>>>(x, ln1g + l * E_, ln1b + l * E_, hbf);

        // fused QKV: wT rows [0,1024)=Wq^T, [1024,2048)=Wk^T, [2048,3072)=Wv^T
        trcvt_k<<<dim3(32, 32), blk, 0, stream>>>(Wq + wE, wT,                       E_, E_);
        trcvt_k<<<dim3(32, 32), blk, 0, stream>>>(Wk + wE, wT + (size_t)1024 * E_,   E_, E_);
        trcvt_k<<<dim3(32, 32), blk, 0, stream>>>(Wv + wE, wT + (size_t)2048 * E_,   E_, E_);
        hgemm_k<128,false,false,false,false,false,false><<<dim3(QKVS/128, MROWS/128), blk, 0, stream>>>(
            hbf, wT, nullptr, nullptr, qkv, MROWS, QKVS, E_);

        attn_k<<<dim3(T_ / 64, H_, B_), blk, 0, stream>>>(qkv, ob);

        trcvt_k<<<dim3(32, 32), blk, 0, stream>>>(Wo + wE, wT, E_, E_);
        hgemm_k<64,false,true,false,true,false,false><<<dim3(E_/64, MROWS/128), blk, 0, stream>>>(
            ob, wT, bo + l * E_, x, x, MROWS, E_, E_);

        ln_k<<<MROWS, blk, 0, stream>>>(x, ln2g + l * E_, ln2b + l * E_, hbf);

        trcvt_k<<<dim3(DFF_/32, E_/32), blk, 0, stream>>>(W1 + (size_t)l * E_ * DFF_, wT, E_, DFF_);
        hgemm_k<128,false,true,true,false,true,false><<<dim3(DFF_/128, MROWS/128), blk, 0, stream>>>(
            hbf, wT, b1 + l * DFF_, nullptr, mid, MROWS, DFF_, E_);

        trcvt_k<<<dim3(E_/32, DFF_/32), blk, 0, stream>>>(W2 + (size_t)l * DFF_ * E_, wT, DFF_, E_);
        hgemm_k<64,false,true,false,true,false,false><<<dim3(E_/64, MROWS/128), blk, 0, stream>>>(
            mid, wT, b2 + l * E_, x, x, MROWS, E_, DFF_);
    }

    ln_k<<<MROWS, blk, 0, stream>>>(x, lnfg, lnfb, hbf);
    // lm_head: B = tok fp32 [V][K] (already N-major/K-contig), converted in-kernel.
    // MXF: blockIdx.x = M so the 16 M-blocks of one n-tile run adjacently (B read ~once).
    hgemm_k<128,true,true,false,false,false,true><<<dim3(MROWS/128, V_/128), blk, 0, stream>>>(
        hbf, tok, lmb, nullptr, d_out, MROWS, V_, E_);
}